// Round 10
// baseline (305.272 us; speedup 1.0000x reference)
//
#include <hip/hip_runtime.h>

// OrthoLinear: out[32,8192] = x @ (dequant int4 W)^T + alpha * x @ CSR^T
// R9 post-mortem: R5 prefetch was NEUTRAL (136->141us, all pipes idle).
// MLP math says latency was never binding (80KB in flight/CU >> 9KB needed).
// New theory: 2.1M device-scope f32 atomicAdds execute memory-side (XCD L2s
// non-coherent); 128 serialized RMWs per hot out-line backpressure the whole
// memory system -- invisible to SQ counters. R10: ZERO-ATOMIC design:
//   prep -> dense (per-g partials, plain stores, no LDS) ->
//   sparse (own partial slice) -> reduce (out = sum of 9 slices).
// Split kernels also give per-phase rocprof timing (ablation for free).

#define IN_F 8192
#define OUT_F 8192
#define NROW 32
#define KSPLIT 8
#define KSEG (IN_F / KSPLIT)   // 1024
#define CHUNKS (KSEG / 32)     // 32
#define SLICE (NROW * OUT_F)   // 262144 floats = 1MB per partial slice

typedef __attribute__((ext_vector_type(8))) short short8v;
typedef __attribute__((ext_vector_type(4))) float f32x4;

union Frag {
  int4 v;
  unsigned int u[4];
  short8v s;
};

__device__ __forceinline__ unsigned int cvt_pk_bf16(float lo, float hi) {
  unsigned int r;
  asm("v_cvt_pk_bf16_f32 %0, %1, %2" : "=v"(r) : "v"(lo), "v"(hi));
  return r;
}

__device__ __forceinline__ unsigned short f2bf(float f) {
  unsigned int u = __float_as_uint(f);
  u += 0x7FFFu + ((u >> 16) & 1u);  // round-to-nearest-even
  return (unsigned short)(u >> 16);
}

// prep: 128 blocks; block b owns k-range [b*64, +64).
// Coalesced x reads -> x_hi/x_lo bf16 stores + LDS-tiled transpose -> xTb
// ([k][n], 64B rows) with coalesced 16B writes.
__global__ __launch_bounds__(256) void prep_kernel(
    const float* __restrict__ x, unsigned short* __restrict__ x_hi,
    unsigned short* __restrict__ x_lo, unsigned short* __restrict__ xTb) {
  __shared__ unsigned short T[64 * 33];
  int tid = threadIdx.x;
  int k0 = blockIdx.x * 64;
  int kk = tid & 63;
  int ng = tid >> 6;
#pragma unroll
  for (int p = 0; p < 8; ++p) {
    int n = p * 4 + ng;
    int idx = n * IN_F + k0 + kk;
    float v = x[idx];
    unsigned short h = f2bf(v);
    float hf = __uint_as_float((unsigned int)h << 16);
    unsigned short l = f2bf(v - hf);
    x_hi[idx] = h;
    x_lo[idx] = l;
    T[kk * 33 + n] = h;
  }
  __syncthreads();
  int kr = tid >> 2, q = tid & 3;
  unsigned int s0 = T[kr * 33 + q * 8 + 0], s1 = T[kr * 33 + q * 8 + 1];
  unsigned int s2 = T[kr * 33 + q * 8 + 2], s3 = T[kr * 33 + q * 8 + 3];
  unsigned int s4 = T[kr * 33 + q * 8 + 4], s5 = T[kr * 33 + q * 8 + 5];
  unsigned int s6 = T[kr * 33 + q * 8 + 6], s7 = T[kr * 33 + q * 8 + 7];
  int4 wv;
  wv.x = (int)(s0 | (s1 << 16));
  wv.y = (int)(s2 | (s3 << 16));
  wv.z = (int)(s4 | (s5 << 16));
  wv.w = (int)(s6 | (s7 << 16));
  ((int4*)xTb)[(size_t)(k0 + kr) * 4 + q] = wv;
}

// dense: grid (128 og x 8 g), 4 waves; wave w owns o-tile [og*64+w*16,+16),
// K-seg [g*1024,+1024). NO LDS, NO atomics: writes part[g][m][o].
__global__ __launch_bounds__(256, 4) void dense_kernel(
    const int* __restrict__ packed, const float* __restrict__ scales,
    const unsigned short* __restrict__ x_hi,
    const unsigned short* __restrict__ x_lo, float* __restrict__ part) {
  int tid = threadIdx.x;
  int lane = tid & 63;
  int w = tid >> 6;
  int og = blockIdx.x >> 3;
  int g = blockIdx.x & 7;
  int lo16 = lane & 15;
  int lhi = lane >> 4;

  int o = og * 64 + w * 16 + lo16;
  int kbeg = g * KSEG;
  const int4* wp = (const int4*)(packed + (size_t)o * (IN_F / 2) + (kbeg >> 1)) + lhi;
  const unsigned short* xh = x_hi + lo16 * IN_F + kbeg + 8 * lhi;
  const unsigned short* xl = x_lo + lo16 * IN_F + kbeg + 8 * lhi;

  f32x4 acc0 = {0.f, 0.f, 0.f, 0.f};
  f32x4 acc1 = {0.f, 0.f, 0.f, 0.f};

  Frag wA, h0A, l0A, h1A, l1A;
  Frag wB, h0B, l0B, h1B, l1B;

#define LOADIN(W_, H0, L0, H1, L1, c)                  \
  W_.v = wp[(c) * 4];                                  \
  H0.v = *(const int4*)(xh + (c) * 32);                \
  L0.v = *(const int4*)(xl + (c) * 32);                \
  H1.v = *(const int4*)(xh + 16 * IN_F + (c) * 32);    \
  L1.v = *(const int4*)(xl + 16 * IN_F + (c) * 32);

#define COMPUTE(W_, H0, L0, H1, L1)                                               \
  {                                                                               \
    Frag b;                                                                       \
    b.u[0] = cvt_pk_bf16((float)(W_.v.x & 15) - 8.0f, (float)(W_.v.x >> 4) - 8.0f); \
    b.u[1] = cvt_pk_bf16((float)(W_.v.y & 15) - 8.0f, (float)(W_.v.y >> 4) - 8.0f); \
    b.u[2] = cvt_pk_bf16((float)(W_.v.z & 15) - 8.0f, (float)(W_.v.z >> 4) - 8.0f); \
    b.u[3] = cvt_pk_bf16((float)(W_.v.w & 15) - 8.0f, (float)(W_.v.w >> 4) - 8.0f); \
    acc0 = __builtin_amdgcn_mfma_f32_16x16x32_bf16(H0.s, b.s, acc0, 0, 0, 0);     \
    acc0 = __builtin_amdgcn_mfma_f32_16x16x32_bf16(L0.s, b.s, acc0, 0, 0, 0);     \
    acc1 = __builtin_amdgcn_mfma_f32_16x16x32_bf16(H1.s, b.s, acc1, 0, 0, 0);     \
    acc1 = __builtin_amdgcn_mfma_f32_16x16x32_bf16(L1.s, b.s, acc1, 0, 0, 0);     \
  }

  LOADIN(wA, h0A, l0A, h1A, l1A, 0)
  for (int c = 0; c < CHUNKS; c += 2) {
    LOADIN(wB, h0B, l0B, h1B, l1B, c + 1)
    COMPUTE(wA, h0A, l0A, h1A, l1A)
    if (c + 2 < CHUNKS) {
      LOADIN(wA, h0A, l0A, h1A, l1A, c + 2)
    }
    COMPUTE(wB, h0B, l0B, h1B, l1B)
  }
#undef LOADIN
#undef COMPUTE

  // single-writer partial store: part[g][m][o]  (C layout: col=lane&15, row=lhi*4+r)
  float sc = scales[o];
  float* ps = part + (size_t)g * SLICE;
#pragma unroll
  for (int r = 0; r < 4; ++r) {
    int m = lhi * 4 + r;
    ps[(size_t)m * OUT_F + o] = sc * acc0[r];
    ps[(size_t)(m + 16) * OUT_F + o] = sc * acc1[r];
  }
}

// sparse: 1024 blocks x 8 rows; wave w owns 2 rows. Writes part[8][m][ro].
__global__ __launch_bounds__(256) void sparse_kernel(
    const float* __restrict__ vals, const int* __restrict__ cols,
    const int* __restrict__ rptr, const float* __restrict__ alphap,
    const unsigned short* __restrict__ xTb, float* __restrict__ part8) {
  __shared__ float red[4][64 * 33];
  int tid = threadIdx.x;
  int lane = tid & 63;
  int w = tid >> 6;
  float alpha = alphap[0];
  float* R = red[w];
#pragma unroll 1
  for (int rr = 0; rr < 2; ++rr) {
    int ro = blockIdx.x * 8 + w * 2 + rr;
    int js = rptr[ro], je = rptr[ro + 1];
    float acc[32];
#pragma unroll
    for (int i = 0; i < 32; ++i) acc[i] = 0.f;

    int j = js + lane;
    float vc = 0.f;
    int cc = 0;
    if (j < je) { vc = vals[j]; cc = cols[j]; }
    while (j < je) {
      int jn = j + 64;
      float vn = 0.f;
      int cn = 0;
      if (jn < je) { vn = vals[jn]; cn = cols[jn]; }
      const int4* xp = (const int4*)(xTb + (size_t)cc * NROW);
      int4 q0 = xp[0], q1 = xp[1], q2 = xp[2], q3 = xp[3];
#define UNP(dw, base)                                                          \
  {                                                                            \
    unsigned int ud = (unsigned int)(dw);                                      \
    acc[base] = fmaf(vc, __uint_as_float(ud << 16), acc[base]);                \
    acc[base + 1] = fmaf(vc, __uint_as_float(ud & 0xFFFF0000u), acc[base + 1]); \
  }
      UNP(q0.x, 0) UNP(q0.y, 2) UNP(q0.z, 4) UNP(q0.w, 6)
      UNP(q1.x, 8) UNP(q1.y, 10) UNP(q1.z, 12) UNP(q1.w, 14)
      UNP(q2.x, 16) UNP(q2.y, 18) UNP(q2.z, 20) UNP(q2.w, 22)
      UNP(q3.x, 24) UNP(q3.y, 26) UNP(q3.z, 28) UNP(q3.w, 30)
#undef UNP
      j = jn;
      vc = vn;
      cc = cn;
    }
#pragma unroll
    for (int i = 0; i < 32; ++i) R[lane * 33 + i] = acc[i];
    int cidx = lane & 31;
    int h = lane >> 5;
    float sum = 0.f;
#pragma unroll
    for (int r2 = 0; r2 < 32; ++r2) sum += R[(h * 32 + r2) * 33 + cidx];
    sum += __shfl_xor(sum, 32, 64);
    if (lane < 32) part8[(size_t)lane * OUT_F + ro] = alpha * sum;
  }
}

// reduce: out = sum of 9 partial slices (also overwrites 0xAA poison).
__global__ __launch_bounds__(256) void reduce_kernel(
    const float* __restrict__ part, float* __restrict__ out) {
  int i = blockIdx.x * 256 + threadIdx.x;  // float4 index, 65536 total
  const float4* p4 = (const float4*)part;
  float4 s = p4[i];
#pragma unroll
  for (int sl = 1; sl < 9; ++sl) {
    float4 t = p4[i + sl * (SLICE / 4)];
    s.x += t.x; s.y += t.y; s.z += t.z; s.w += t.w;
  }
  ((float4*)out)[i] = s;
}

extern "C" void kernel_launch(void* const* d_in, const int* in_sizes, int n_in,
                              void* d_out, int out_size, void* d_ws, size_t ws_size,
                              hipStream_t stream) {
  const float* x = (const float*)d_in[0];
  const int* packed = (const int*)d_in[1];
  const float* scales = (const float*)d_in[2];
  const float* vals = (const float*)d_in[3];
  const int* cols = (const int*)d_in[4];
  const int* rptr = (const int*)d_in[5];
  const float* alphap = (const float*)d_in[6];
  float* out = (float*)d_out;

  unsigned short* x_hi = (unsigned short*)d_ws;            // 512 KB
  unsigned short* x_lo = x_hi + NROW * IN_F;               // 512 KB
  unsigned short* xTb = x_lo + NROW * IN_F;                // 512 KB
  float* part = (float*)(xTb + NROW * IN_F);               // 9 x 1 MB

  prep_kernel<<<IN_F / 64, 256, 0, stream>>>(x, x_hi, x_lo, xTb);
  dense_kernel<<<(OUT_F / 64) * KSPLIT, 256, 0, stream>>>(
      packed, scales, x_hi, x_lo, part);
  sparse_kernel<<<OUT_F / 8, 256, 0, stream>>>(
      vals, cols, rptr, alphap, xTb, part + (size_t)8 * SLICE);
  reduce_kernel<<<(SLICE / 4) / 256, 256, 0, stream>>>(part, out);
}

// Round 13
// 263.797 us; speedup vs baseline: 1.1572x; 1.1572x over previous
//
#include <hip/hip_runtime.h>

// OrthoLinear: out[32,8192] = x @ (dequant int4 W)^T + alpha * x @ CSR^T
// R10 post-mortem: zero-atomic dense still 100us, VGPR_Count=32 => compiler
// SANK the register prefetch (needs >=80 VGPR); in-flight = 80B/wave x 16
// waves/CU = 1.3KB => 0.9 TB/s == measured. Latency-bound by load sinking.
// R11: dense v2 = global_load_lds staging (fire-and-forget, vmcnt-tracked,
// no VGPR), double-buffered 32KB LDS, 16 K-steps, XOR-swizzle (row&7)<<4
// applied on BOTH sides (pre-swizzled global source + swizzled ds_read).
// prep/sparse/reduce unchanged from R10 (proven correct, unmeasured).
// R12/R13: resubmit unchanged (bench never ran: GPUAcquisitionTimeout).
// Offline audits passed: swizzle involution both sides; per-wave 1KB LDS
// dest regions disjoint; vmcnt(4) drains current buffer, keeps next in flight.

#define IN_F 8192
#define OUT_F 8192
#define NROW 32
#define KSPLIT 8
#define KSEG (IN_F / KSPLIT)   // 1024
#define KS 64                  // k per stage step
#define NSTEP (KSEG / KS)      // 16
#define PK_TILE 8192           // 64 rows x 128 B packed bytes per step
#define X_TILE 4096            // 32 rows x 128 B bf16 per step
#define BUF_SZ (PK_TILE + 2 * X_TILE)  // 16384
#define SLICE (NROW * OUT_F)   // 1MB partial slice

typedef __attribute__((ext_vector_type(8))) short short8v;
typedef __attribute__((ext_vector_type(4))) float f32x4;

union Frag {
  int4 v;
  unsigned int u[4];
  short8v s;
};

__device__ __forceinline__ unsigned int cvt_pk_bf16(float lo, float hi) {
  unsigned int r;
  asm("v_cvt_pk_bf16_f32 %0, %1, %2" : "=v"(r) : "v"(lo), "v"(hi));
  return r;
}

__device__ __forceinline__ unsigned short f2bf(float f) {
  unsigned int u = __float_as_uint(f);
  u += 0x7FFFu + ((u >> 16) & 1u);
  return (unsigned short)(u >> 16);
}

// prep: unchanged from R10.
__global__ __launch_bounds__(256) void prep_kernel(
    const float* __restrict__ x, unsigned short* __restrict__ x_hi,
    unsigned short* __restrict__ x_lo, unsigned short* __restrict__ xTb) {
  __shared__ unsigned short T[64 * 33];
  int tid = threadIdx.x;
  int k0 = blockIdx.x * 64;
  int kk = tid & 63;
  int ng = tid >> 6;
#pragma unroll
  for (int p = 0; p < 8; ++p) {
    int n = p * 4 + ng;
    int idx = n * IN_F + k0 + kk;
    float v = x[idx];
    unsigned short h = f2bf(v);
    float hf = __uint_as_float((unsigned int)h << 16);
    unsigned short l = f2bf(v - hf);
    x_hi[idx] = h;
    x_lo[idx] = l;
    T[kk * 33 + n] = h;
  }
  __syncthreads();
  int kr = tid >> 2, q = tid & 3;
  unsigned int s0 = T[kr * 33 + q * 8 + 0], s1 = T[kr * 33 + q * 8 + 1];
  unsigned int s2 = T[kr * 33 + q * 8 + 2], s3 = T[kr * 33 + q * 8 + 3];
  unsigned int s4 = T[kr * 33 + q * 8 + 4], s5 = T[kr * 33 + q * 8 + 5];
  unsigned int s6 = T[kr * 33 + q * 8 + 6], s7 = T[kr * 33 + q * 8 + 7];
  int4 wv;
  wv.x = (int)(s0 | (s1 << 16));
  wv.y = (int)(s2 | (s3 << 16));
  wv.z = (int)(s4 | (s5 << 16));
  wv.w = (int)(s6 | (s7 << 16));
  ((int4*)xTb)[(size_t)(k0 + kr) * 4 + q] = wv;
}

// dense v2: async LDS staging. Block (og,g): 64 o-rows, K-seg [g*1024,+1024).
// LDS buf layout: [0,8192) packed [64 rows][128B]; [8192,12288) x_hi [32][128];
// [12288,16384) x_lo [32][128]. All rows XOR-swizzled: byte ^= ((row&7)<<4).
__global__ __launch_bounds__(256) void dense_kernel(
    const int* __restrict__ packed, const float* __restrict__ scales,
    const unsigned short* __restrict__ x_hi,
    const unsigned short* __restrict__ x_lo, float* __restrict__ part) {
  __shared__ char lds[2][BUF_SZ];
  int tid = threadIdx.x;
  int lane = tid & 63;
  int w = tid >> 6;
  int og = blockIdx.x >> 3;
  int g = blockIdx.x & 7;
  int lo16 = lane & 15;
  int lhi = lane >> 4;

  // staging sources (pre-swizzled so the linear LDS write lands swizzled)
  int L0 = tid * 16;                       // linear byte in round-0 region
  int pr0 = L0 >> 7;                       // packed tile row 0..31
  int pb0 = (L0 & 127) ^ ((pr0 & 7) << 4); // swizzled source byte
  const char* pkB = (const char*)packed;   // packed row = 16384 B
  const char* psrc0 = pkB + (size_t)(og * 64 + pr0) * 16384 + g * 2048 + pb0;
  const char* psrc1 = pkB + (size_t)(og * 64 + pr0 + 32) * 16384 + g * 2048 + pb0;
  int xr = tid >> 3;                       // x tile row 0..31
  int xb = ((tid & 7) * 16) ^ ((xr & 7) << 4);
  const char* xhsrc = (const char*)x_hi + (size_t)xr * (IN_F * 2) + g * 2048 + xb;
  const char* xlsrc = (const char*)x_lo + (size_t)xr * (IN_F * 2) + g * 2048 + xb;
  int woff = w * 1024;                     // wave-uniform LDS dest offset

#define STAGE(s, b)                                                          \
  {                                                                          \
    int so_ = (s) * 128;                                                     \
    __builtin_amdgcn_global_load_lds((const unsigned int*)(psrc0 + so_),     \
        (unsigned int*)(&lds[b][0] + woff), 16, 0, 0);                       \
    __builtin_amdgcn_global_load_lds((const unsigned int*)(psrc1 + so_),     \
        (unsigned int*)(&lds[b][4096] + woff), 16, 0, 0);                    \
    __builtin_amdgcn_global_load_lds((const unsigned int*)(xhsrc + so_),     \
        (unsigned int*)(&lds[b][PK_TILE] + woff), 16, 0, 0);                 \
    __builtin_amdgcn_global_load_lds((const unsigned int*)(xlsrc + so_),     \
        (unsigned int*)(&lds[b][PK_TILE + X_TILE] + woff), 16, 0, 0);        \
  }

  f32x4 acc0 = {0.f, 0.f, 0.f, 0.f};
  f32x4 acc1 = {0.f, 0.f, 0.f, 0.f};
  int prow = w * 16 + lo16;               // packed tile row this lane reads
  int pswz = (prow & 7) << 4;
  int xswz = (lo16 & 7) << 4;             // rows lo16 and lo16+16: same &7

#define COMPCHUNK(b, cp)                                                      \
  {                                                                           \
    int pby = (cp) * 64 + 16 * lhi;                                           \
    Frag bb, a0h, a0l, a1h, a1l;                                              \
    bb.v = *(const int4*)&lds[b][prow * 128 + (pby ^ pswz)];                  \
    a0h.v = *(const int4*)&lds[b][PK_TILE + lo16 * 128 + (pby ^ xswz)];       \
    a0l.v = *(const int4*)&lds[b][PK_TILE + X_TILE + lo16 * 128 + (pby ^ xswz)]; \
    a1h.v = *(const int4*)&lds[b][PK_TILE + (lo16 + 16) * 128 + (pby ^ xswz)];   \
    a1l.v = *(const int4*)&lds[b][PK_TILE + X_TILE + (lo16 + 16) * 128 + (pby ^ xswz)]; \
    Frag bf;                                                                  \
    bf.u[0] = cvt_pk_bf16((float)(bb.v.x & 15) - 8.0f, (float)(bb.v.x >> 4) - 8.0f); \
    bf.u[1] = cvt_pk_bf16((float)(bb.v.y & 15) - 8.0f, (float)(bb.v.y >> 4) - 8.0f); \
    bf.u[2] = cvt_pk_bf16((float)(bb.v.z & 15) - 8.0f, (float)(bb.v.z >> 4) - 8.0f); \
    bf.u[3] = cvt_pk_bf16((float)(bb.v.w & 15) - 8.0f, (float)(bb.v.w >> 4) - 8.0f); \
    acc0 = __builtin_amdgcn_mfma_f32_16x16x32_bf16(a0h.s, bf.s, acc0, 0, 0, 0); \
    acc0 = __builtin_amdgcn_mfma_f32_16x16x32_bf16(a0l.s, bf.s, acc0, 0, 0, 0); \
    acc1 = __builtin_amdgcn_mfma_f32_16x16x32_bf16(a1h.s, bf.s, acc1, 0, 0, 0); \
    acc1 = __builtin_amdgcn_mfma_f32_16x16x32_bf16(a1l.s, bf.s, acc1, 0, 0, 0); \
  }

  STAGE(0, 0)
  for (int s = 0; s < NSTEP; ++s) {
    int b = s & 1;
    if (s + 1 < NSTEP) {
      STAGE(s + 1, (s + 1) & 1)
      asm volatile("s_waitcnt vmcnt(4)" ::: "memory");
    } else {
      asm volatile("s_waitcnt vmcnt(0)" ::: "memory");
    }
    __syncthreads();
    COMPCHUNK(b, 0)
    COMPCHUNK(b, 1)
    __syncthreads();
  }
#undef STAGE
#undef COMPCHUNK

  // partial store: part[g][m][o]  (C layout: col=lane&15 = o, row=lhi*4+r = m)
  int o = og * 64 + w * 16 + lo16;
  float sc = scales[o];
  float* ps = part + (size_t)g * SLICE;
#pragma unroll
  for (int r = 0; r < 4; ++r) {
    int m = lhi * 4 + r;
    ps[(size_t)m * OUT_F + o] = sc * acc0[r];
    ps[(size_t)(m + 16) * OUT_F + o] = sc * acc1[r];
  }
}

// sparse: unchanged from R10.
__global__ __launch_bounds__(256) void sparse_kernel(
    const float* __restrict__ vals, const int* __restrict__ cols,
    const int* __restrict__ rptr, const float* __restrict__ alphap,
    const unsigned short* __restrict__ xTb, float* __restrict__ part8) {
  __shared__ float red[4][64 * 33];
  int tid = threadIdx.x;
  int lane = tid & 63;
  int w = tid >> 6;
  float alpha = alphap[0];
  float* R = red[w];
#pragma unroll 1
  for (int rr = 0; rr < 2; ++rr) {
    int ro = blockIdx.x * 8 + w * 2 + rr;
    int js = rptr[ro], je = rptr[ro + 1];
    float acc[32];
#pragma unroll
    for (int i = 0; i < 32; ++i) acc[i] = 0.f;

    int j = js + lane;
    float vc = 0.f;
    int cc = 0;
    if (j < je) { vc = vals[j]; cc = cols[j]; }
    while (j < je) {
      int jn = j + 64;
      float vn = 0.f;
      int cn = 0;
      if (jn < je) { vn = vals[jn]; cn = cols[jn]; }
      const int4* xp = (const int4*)(xTb + (size_t)cc * NROW);
      int4 q0 = xp[0], q1 = xp[1], q2 = xp[2], q3 = xp[3];
#define UNP(dw, base)                                                          \
  {                                                                            \
    unsigned int ud = (unsigned int)(dw);                                      \
    acc[base] = fmaf(vc, __uint_as_float(ud << 16), acc[base]);                \
    acc[base + 1] = fmaf(vc, __uint_as_float(ud & 0xFFFF0000u), acc[base + 1]); \
  }
      UNP(q0.x, 0) UNP(q0.y, 2) UNP(q0.z, 4) UNP(q0.w, 6)
      UNP(q1.x, 8) UNP(q1.y, 10) UNP(q1.z, 12) UNP(q1.w, 14)
      UNP(q2.x, 16) UNP(q2.y, 18) UNP(q2.z, 20) UNP(q2.w, 22)
      UNP(q3.x, 24) UNP(q3.y, 26) UNP(q3.z, 28) UNP(q3.w, 30)
#undef UNP
      j = jn;
      vc = vn;
      cc = cn;
    }
#pragma unroll
    for (int i = 0; i < 32; ++i) R[lane * 33 + i] = acc[i];
    int cidx = lane & 31;
    int h = lane >> 5;
    float sum = 0.f;
#pragma unroll
    for (int r2 = 0; r2 < 32; ++r2) sum += R[(h * 32 + r2) * 33 + cidx];
    sum += __shfl_xor(sum, 32, 64);
    if (lane < 32) part8[(size_t)lane * OUT_F + ro] = alpha * sum;
  }
}

// reduce: unchanged from R10.
__global__ __launch_bounds__(256) void reduce_kernel(
    const float* __restrict__ part, float* __restrict__ out) {
  int i = blockIdx.x * 256 + threadIdx.x;
  const float4* p4 = (const float4*)part;
  float4 s = p4[i];
#pragma unroll
  for (int sl = 1; sl < 9; ++sl) {
    float4 t = p4[i + sl * (SLICE / 4)];
    s.x += t.x; s.y += t.y; s.z += t.z; s.w += t.w;
  }
  ((float4*)out)[i] = s;
}

extern "C" void kernel_launch(void* const* d_in, const int* in_sizes, int n_in,
                              void* d_out, int out_size, void* d_ws, size_t ws_size,
                              hipStream_t stream) {
  const float* x = (const float*)d_in[0];
  const int* packed = (const int*)d_in[1];
  const float* scales = (const float*)d_in[2];
  const float* vals = (const float*)d_in[3];
  const int* cols = (const int*)d_in[4];
  const int* rptr = (const int*)d_in[5];
  const float* alphap = (const float*)d_in[6];
  float* out = (float*)d_out;

  unsigned short* x_hi = (unsigned short*)d_ws;            // 512 KB
  unsigned short* x_lo = x_hi + NROW * IN_F;               // 512 KB
  unsigned short* xTb = x_lo + NROW * IN_F;                // 512 KB
  float* part = (float*)(xTb + NROW * IN_F);               // 9 x 1 MB

  prep_kernel<<<IN_F / 64, 256, 0, stream>>>(x, x_hi, x_lo, xTb);
  dense_kernel<<<(OUT_F / 64) * KSPLIT, 256, 0, stream>>>(
      packed, scales, x_hi, x_lo, part);
  sparse_kernel<<<OUT_F / 8, 256, 0, stream>>>(
      vals, cols, rptr, alphap, xTb, part + (size_t)8 * SLICE);
  reduce_kernel<<<(SLICE / 4) / 256, 256, 0, stream>>>(part, out);
}